// Round 9
// baseline (256.353 us; speedup 1.0000x reference)
//
#include <hip/hip_runtime.h>
#include <cmath>

// SSIM over (32,3,512,512) f32 pairs, 11x11 separable gaussian, valid conv,
// scalar mean output. Round 14: packed-FP32 math. R13 counters: VALU busy
// ~67us of 117 vs a 27us pure-FMA floor, LDS pipe ~55us -> issue-bound on
// VALU instruction count. All conv FMAs now emit v_pk_fma_f32 (VOP3P, 2
// FMA/instr) via inline asm: the f4 channel vector (x, y, x^2+y^2, x*y)
// splits into two v2 pairs; v-conv pairs alias ds_read_b128 quad halves
// (free), h-conv pays 2 v_movs/tap to form {x,y} (net win ~2/3 of h FMAs).
// Everything else (persistent half-strips, 48-row raw ring + A/B DMA
// half-batches, 44-row hS ring, counted-vmcnt barriers, conflict-free maps,
// epilogue) identical to R13 (117us, 4 blk/CU).

#define HH 512
#define WW 512
#define OH 502           // 512 - 11 + 1
#define OW 502
#define NC 96            // 32 * 3
#define TXS 32           // strip width (output cols)
#define BROWS 32         // output rows per iteration
#define NIT 8            // 8 * 32 = 256 rows per half-strip
#define RAWR 48          // raw ring rows (three 16-row thirds)
#define RAWP 11          // raw row stride in f4s (odd -> conflict-free reads)
#define HSR 44           // hS ring rows (42 live; mod-44 wrap <= 2-way = free)
#define HP4 33           // hS row stride in f4s (528 B -> 4-bank row rotation)
#define GX 16
#define NSLOT 64         // f64 accumulator slots, 64 B apart

typedef float f4 __attribute__((ext_vector_type(4)));
typedef float v2 __attribute__((ext_vector_type(2)));

struct GaussW { float g[11]; };

static __device__ __forceinline__ f4 sp(float s) { return (f4){s, s, s, s}; }

// acc = g2 * p + acc, two f32 lanes per instruction (VOP3P packed FP32).
static __device__ __forceinline__ void pkfma(v2& acc, v2 g2, v2 p) {
    asm("v_pk_fma_f32 %0, %1, %2, %0" : "+v"(acc) : "v"(g2), "v"(p));
}

#define FENCE() asm volatile("" ::: "memory")

__global__ __launch_bounds__(256, 4) void ssim_kernel(
        const float* __restrict__ X, const float* __restrict__ Y,
        double* __restrict__ acc, GaussW gw) {
    // rawS: [a][rslot][c4] flat, slot(local row) = (row+6) % 48; 11 f4/row
    // (44 cols; cols 42,43 loaded-unused). hS[s][c]: s = row % 44.
    __shared__ f4 rawS[2 * RAWR * RAWP];         // 16896 B
    __shared__ f4 hS[HSR][HP4];                  // 23232 B
    __shared__ double wsum[4];                   // total 40160 B -> 4 blk/CU

    const int tid = threadIdx.x;
    const int C0 = blockIdx.x * TXS;
    const int R0 = blockIdx.y * (BROWS * NIT);   // 0 or 256 (half-strip)
    const float* Xp = X + (size_t)blockIdx.z * (HH * WW);
    const float* Yp = Y + (size_t)blockIdx.z * (HH * WW);

    // One DMA slot: row/col clamped per-lane in the SRC address (edge strip
    // and bottom tail read duplicated data -> finite, consumers masked).
    auto dma1 = [&](int a, int slot_f4, int grow, int c4) {
        const float* bp  = a ? Yp : Xp;
        const float* src = bp + (size_t)min(grow, HH - 1) * WW
                              + min(C0 + 4 * c4, WW - 4);
        f4* dst = rawS + a * (RAWR * RAWP) + slot_f4;  // wave-uniform base
        __builtin_amdgcn_global_load_lds(
            (const __attribute__((address_space(1))) void*)src,
            (__attribute__((address_space(3))) void*)dst, 16, 0, 0);
    };

    // 16-row DMA half-batch: h=0 -> local rows 32i+42.., h=1 -> 32i+58..
    // Target third base tb = ((br+6)%48)*11; idx linear in tid -> dst is
    // wave-uniform base + lane*16 (HW requirement).
    auto dma_half = [&](int i, int h) {
        const int br = 32 * i + 42 + 16 * h;
        const int tb = ((br + 6) % RAWR) * RAWP; // 0 / 176 / 352
        if (tid < 16 * RAWP) {                   // 176
            int o = tid / RAWP, c4 = tid - o * RAWP;
            int db = tb + (tid & ~63);
            dma1(0, db, R0 + br + o, c4);
            dma1(1, db, R0 + br + o, c4);
        }
    };

    // h-conv one task (4 output cols) from raw ring, write hS ring.
    // Task map keeps row in LOW 3 bits; ring wraps preserve the residue
    // maps: raw (3rs+cg)&7 distinct (48=0 mod 8), hS <=2-way (44=4 mod 8).
    auto htask = [&](int o, int cg, int rbm, int bm) {
        int rs = rbm + o; if (rs >= RAWR) rs -= RAWR;
        int hs = bm + o;  if (hs >= HSR)  hs -= HSR;
        const int ib = rs * RAWP + cg;
        f4 x0 = rawS[ib + 0], x1 = rawS[ib + 1];
        f4 x2 = rawS[ib + 2], x3 = rawS[ib + 3];
        f4 y0 = rawS[RAWR * RAWP + ib + 0], y1 = rawS[RAWR * RAWP + ib + 1];
        f4 y2 = rawS[RAWR * RAWP + ib + 2], y3 = rawS[RAWR * RAWP + ib + 3];
        float xv[16], yv[16];
        #pragma unroll
        for (int q = 0; q < 4; ++q) {
            xv[q] = x0[q]; xv[4 + q] = x1[q]; xv[8 + q] = x2[q]; xv[12 + q] = x3[q];
            yv[q] = y0[q]; yv[4 + q] = y1[q]; yv[8 + q] = y2[q]; yv[12 + q] = y3[q];
        }
        v2 a01[4], a23[4];
        #pragma unroll
        for (int j = 0; j < 4; ++j) { a01[j] = (v2){0.f, 0.f}; a23[j] = (v2){0.f, 0.f}; }
        #pragma unroll
        for (int k = 0; k < 14; ++k) {
            float x = xv[k], y = yv[k];
            v2 p01 = (v2){x, y};                 // raw domain (sum(g)=1 lets
            v2 p23 = (v2){fmaf(x, x, y * y), x * y};  // normalization fold)
            #pragma unroll
            for (int j = 0; j < 4; ++j) {
                int u = k - j;
                if (u >= 0 && u < 11) {          // statically resolved
                    v2 g2 = (v2){gw.g[u], gw.g[u]};
                    pkfma(a01[j], g2, p01);
                    pkfma(a23[j], g2, p23);
                }
            }
        }
        #pragma unroll
        for (int j = 0; j < 4; ++j)              // conflict-free b128 writes
            hS[hs][4 * cg + j] = (f4){a01[j].x, a01[j].y, a23[j].x, a23[j].y};
    };

    // ---- warmup: stage local rows [0,42) -> slots 6..47 (f4 66..527)
    #pragma unroll
    for (int k = 0; k < 2; ++k) {
        int idx = (k << 8) + tid;
        if (idx < 42 * RAWP) {                   // 462
            int o = idx / RAWP, c4 = idx - o * RAWP;
            int db = 6 * RAWP + (k << 8) + (tid & ~63);
            dma1(0, db, R0 + o, c4);
            dma1(1, db, R0 + o, c4);
        }
    }
    asm volatile("s_waitcnt vmcnt(0)" ::: "memory");
    __builtin_amdgcn_s_barrier();
    FENCE();

    // ---- main loop: 8 iterations of 32 output rows
    double tsum = 0.0;
    const int c  = tid & 31;
    const int rb = (tid >> 5) * 4;               // 0,4,...,28

    for (int i = 0; i < NIT; ++i) {
        if (i >= 1 && i <= NIT - 2) dma_half(i, 0);  // batch A: hides h+v

        // h-conv: iter 0 = local rows [0,42) (336 tasks); else [32i+10,+42).
        const int rbm = (i == 0) ? 6 : ((32 * i + 16) % RAWR);
        const int bm  = (i == 0) ? 0 : ((32 * i + 10) % HSR);
        {
            const int cg = (tid >> 3) & 7;
            const int o  = (tid & 7) | ((tid >> 6) << 3);
            htask(o, cg, rbm, bm);
            if (i == 0) {
                if (tid < 64) htask(32 + (tid & 7), (tid >> 3) & 7, rbm, bm);
                if (tid < 16) htask(40 + (tid & 1), (tid >> 1) & 7, rbm, bm);
            }
        }
        asm volatile("s_waitcnt lgkmcnt(0)" ::: "memory");  // publish hS
        __builtin_amdgcn_s_barrier();            // NO vmcnt drain here
        FENCE();
        if (i == 0) dma_half(0, 0);              // iter-0 A: slots busy pre-mid
        if (i <= NIT - 2) dma_half(i, 1);        // batch B: hides under v

        // v-conv + SSIM epilogue: 1 col x 4 rows per thread. Packed pairs
        // alias the b128 quad halves -> zero marshalling movs.
        const int vb = (32 * i) % HSR;
        v2 A01[4], A23[4];
        #pragma unroll
        for (int j = 0; j < 4; ++j) { A01[j] = (v2){0.f, 0.f}; A23[j] = (v2){0.f, 0.f}; }
        #pragma unroll
        for (int k = 0; k < 14; ++k) {
            int s = vb + rb + k; if (s >= HSR) s -= HSR;
            f4 v = hS[s][c];                     // one ds_read_b128 per tap-row
            v2 v01 = (v2){v.x, v.y};
            v2 v23 = (v2){v.z, v.w};
            #pragma unroll
            for (int j = 0; j < 4; ++j) {
                int u = k - j;
                if (u >= 0 && u < 11) {
                    v2 g2 = (v2){gw.g[u], gw.g[u]};
                    pkfma(A01[j], g2, v01);
                    pkfma(A23[j], g2, v23);
                }
            }
        }
        const float C1 = 1.0e-4f;
        const float C2 = 9.0e-4f;
        float nn[4], dd[4];
        #pragma unroll
        for (int j = 0; j < 4; ++j) {
            float cx = A01[j].x, cy = A01[j].y;
            float cs = A23[j].x, cp = A23[j].y;
            float t1 = cx + 1.f, t2 = cy + 1.f;          // 2*mu1, 2*mu2
            float num1 = fmaf(t1 * t2, 0.5f, C1);        // 2*mu1*mu2 + C1
            float den1 = fmaf(fmaf(t2, t2, t1 * t1), 0.25f, C1);
            float num2 = fmaf(cp - cx * cy, 0.5f, C2);          // 2*sig12 + C2
            float den2 = fmaf(cs - fmaf(cx, cx, cy * cy), 0.25f, C2);
            bool valid = (R0 + 32 * i + rb + j < OH) & (C0 + c < OW);
            nn[j] = valid ? num1 * num2 : 0.f;   // clamped-junk rows land here
            dd[j] = valid ? den1 * den2 : 1.f;   // and are replaced -> safe
        }
        // 1 divide / 4 outputs via common denominator
        // (dd >= C1*C2 ~ 1e-7; 4-products >= ~6e-29 stay normal in f32)
        float d01 = dd[0] * dd[1], d23 = dd[2] * dd[3];
        float s01 = fmaf(nn[0], dd[1], nn[1] * dd[0]);
        float s23 = fmaf(nn[2], dd[3], nn[3] * dd[2]);
        tsum += (double)(fmaf(s01, d23, s23 * d01) / (d01 * d23));

        // end-of-iter: drain this iter's DMA (A flew over h+v, B over v),
        // and protect hS/raw rings before next iter overwrites.
        asm volatile("s_waitcnt vmcnt(0) lgkmcnt(0)" ::: "memory");
        __builtin_amdgcn_s_barrier();
        FENCE();
    }

    // block reduction (double) + one f64 atomic into a strided slot
    #pragma unroll
    for (int off = 32; off > 0; off >>= 1)
        tsum += __shfl_down(tsum, off, 64);
    if ((tid & 63) == 0) wsum[tid >> 6] = tsum;
    __syncthreads();
    if (tid == 0) {
        int slot = (blockIdx.x + blockIdx.y * GX + blockIdx.z * GX * 2)
                   & (NSLOT - 1);
        atomicAdd(&acc[slot * 8], wsum[0] + wsum[1] + wsum[2] + wsum[3]);
    }
}

__global__ void ssim_finalize(const double* __restrict__ acc,
                              float* __restrict__ out) {
    int lane = threadIdx.x;                      // 64 threads, one slot each
    double t = acc[lane * 8];
    #pragma unroll
    for (int off = 32; off > 0; off >>= 1)
        t += __shfl_down(t, off, 64);
    if (lane == 0)
        out[0] = (float)(t * (1.0 / (double)((long long)NC * OH * OW)));
}

extern "C" void kernel_launch(void* const* d_in, const int* in_sizes, int n_in,
                              void* d_out, int out_size, void* d_ws, size_t ws_size,
                              hipStream_t stream) {
    const float* X = (const float*)d_in[0];
    const float* Y = (const float*)d_in[1];
    float* out = (float*)d_out;
    double* acc = (double*)d_ws;                 // 64 slots x 64 B = 4 KB

    // d_ws is re-poisoned to 0xAA before every timed launch: zero the slots.
    hipMemsetAsync(d_ws, 0, NSLOT * 64, stream);

    // Gaussian weights (win=11, sigma=1.5), computed in f64, passed by value.
    GaussW gw;
    {
        double g[11], s = 0.0;
        for (int i = 0; i < 11; ++i) {
            double d = (double)(i - 5);
            g[i] = exp(-d * d / (2.0 * 1.5 * 1.5));
            s += g[i];
        }
        for (int i = 0; i < 11; ++i) gw.g[i] = (float)(g[i] / s);
    }

    dim3 grid(GX, 2, NC);
    ssim_kernel<<<grid, dim3(256), 0, stream>>>(X, Y, acc, gw);
    ssim_finalize<<<1, dim3(64), 0, stream>>>(acc, out);
}

// Round 11
// 248.287 us; speedup vs baseline: 1.0325x; 1.0325x over previous
//
#include <hip/hip_runtime.h>
#include <cmath>

// SSIM over (32,3,512,512) f32 pairs, 11x11 separable gaussian, valid conv,
// scalar mean output. Round 16 = Round 15 resubmit (container infra failure,
// no dispatch record; tail-carry/race/slot-liveness re-audited clean).
// Static hS window + register tail-carry. R14 proved v_pk_fma_f32 is
// half-rate on CDNA4 (FP32 peak 157.3 TF == scalar SIMD-32 issue rate) ->
// scalar FMA. Remaining overhead: per-k ring addressing in v-conv (~4
// VALU/LDS-read + serialized issue). Fix: v-window pinned at fixed phys
// rows 0..41. h(i) writes image rows 32i+10..41 to phys 10..41 (static).
// The 10-row tail (phys 0..9) is carried in REGISTERS: during v(i-1),
// groups rb=20/24/28 retain phys 32..33/34..37/38..41 (2/4/4 f4) and write
// them to phys 0..9 at the start of h(i) (disjoint from h's writes ->
// race-free, no extra barrier). v-conv = 14 ds_read_b128 at immediate
// offsets from a loop-invariant base: zero per-k VALU, burst-issued reads.
// hS 44->42 rows; LDS 39.1 KB -> 4 blocks/CU. Raw 48-row thirds ring + A/B
// DMA half-batches + counted-vmcnt barriers unchanged from R13.

#define HH 512
#define WW 512
#define OH 502           // 512 - 11 + 1
#define OW 502
#define NC 96            // 32 * 3
#define TXS 32           // strip width (output cols)
#define BROWS 32         // output rows per iteration
#define NIT 8            // 8 * 32 = 256 rows per half-strip
#define RAWR 48          // raw ring rows (three 16-row thirds)
#define RAWP 11          // raw row stride in f4s (odd -> conflict-free reads)
#define NRAWF4 (RAWR*RAWP)  // 528 f4 per array
#define HSROWS 42        // hS rows, FIXED window (no ring)
#define HP4 33           // hS row stride in f4s (528 B -> 4-bank row rotation)
#define GX 16
#define NSLOT 64         // f64 accumulator slots, 64 B apart

typedef float f4 __attribute__((ext_vector_type(4)));

struct GaussW { float g[11]; };

static __device__ __forceinline__ f4 sp(float s) { return (f4){s, s, s, s}; }

#define FENCE() asm volatile("" ::: "memory")

__global__ __launch_bounds__(256, 4) void ssim_kernel(
        const float* __restrict__ X, const float* __restrict__ Y,
        double* __restrict__ acc, GaussW gw) {
    // rawS: [a][rslot][c4] flat, slot(local row) = (row+6) % 48; 11 f4/row.
    // hS[p][c]: phys row p = image row - 32i (fixed window).
    __shared__ f4 rawS[2 * NRAWF4];              // 16896 B
    __shared__ f4 hS[HSROWS][HP4];               // 22176 B
    __shared__ double wsum[4];                   // total 39104 B -> 4 blk/CU

    const int tid = threadIdx.x;
    const int C0 = blockIdx.x * TXS;
    const int R0 = blockIdx.y * (BROWS * NIT);   // 0 or 256 (half-strip)
    const float* Xp = X + (size_t)blockIdx.z * (HH * WW);
    const float* Yp = Y + (size_t)blockIdx.z * (HH * WW);

    // One DMA slot: row/col clamped per-lane in the SRC address (edge strip
    // and bottom tail read duplicated data -> finite, consumers masked).
    auto dma1 = [&](int a, int slot_f4, int grow, int c4) {
        const float* bp  = a ? Yp : Xp;
        const float* src = bp + (size_t)min(grow, HH - 1) * WW
                              + min(C0 + 4 * c4, WW - 4);
        f4* dst = rawS + a * NRAWF4 + slot_f4;   // wave-uniform base
        __builtin_amdgcn_global_load_lds(
            (const __attribute__((address_space(1))) void*)src,
            (__attribute__((address_space(3))) void*)dst, 16, 0, 0);
    };

    // 16-row DMA half-batch: h=0 -> local rows 32i+42.., h=1 -> 32i+58..
    // Third base tb = ((br+6)%48)*11 (wave-uniform SALU); dst linear in tid.
    auto dma_half = [&](int i, int h) {
        const int br = 32 * i + 42 + 16 * h;
        const int tb = ((br + 6) % RAWR) * RAWP; // 0 / 176 / 352
        if (tid < 16 * RAWP) {                   // 176
            int o = tid / RAWP, c4 = tid - o * RAWP;
            int db = tb + (tid & ~63);
            dma1(0, db, R0 + br + o, c4);
            dma1(1, db, R0 + br + o, c4);
        }
    };

    // h-conv one task (4 output cols) from raw ring, write hS at STATIC phys
    // row hs (= hsbase + o, compile-time-affine). Task map keeps row in LOW
    // 3 bits -> 8-lane phases: raw reads & hS writes <= 2-way = free (m136).
    auto htask = [&](int o, int cg, int rbm, int hsbase) {
        int rs = rbm + o; if (rs >= RAWR) rs -= RAWR;
        const int hs = hsbase + o;
        const int ib = rs * RAWP + cg;
        f4 x0 = rawS[ib + 0], x1 = rawS[ib + 1];
        f4 x2 = rawS[ib + 2], x3 = rawS[ib + 3];
        f4 y0 = rawS[NRAWF4 + ib + 0], y1 = rawS[NRAWF4 + ib + 1];
        f4 y2 = rawS[NRAWF4 + ib + 2], y3 = rawS[NRAWF4 + ib + 3];
        float xv[16], yv[16];
        #pragma unroll
        for (int q = 0; q < 4; ++q) {
            xv[q] = x0[q]; xv[4 + q] = x1[q]; xv[8 + q] = x2[q]; xv[12 + q] = x3[q];
            yv[q] = y0[q]; yv[4 + q] = y1[q]; yv[8 + q] = y2[q]; yv[12 + q] = y3[q];
        }
        f4 a0v = sp(0.f), a1v = sp(0.f), a2v = sp(0.f), a3v = sp(0.f);
        #pragma unroll
        for (int k = 0; k < 14; ++k) {
            float x = xv[k], y = yv[k];
            f4 P;
            P.x = x; P.y = y;
            P.z = fmaf(x, x, y * y);             // raw domain (sum(g)=1 lets
            P.w = x * y;                         // normalization fold into epi)
            #pragma unroll
            for (int j = 0; j < 4; ++j) {
                int u = k - j;
                if (u >= 0 && u < 11) {          // statically resolved
                    f4 G = sp(gw.g[u]);
                    if (j == 0) a0v = __builtin_elementwise_fma(G, P, a0v);
                    if (j == 1) a1v = __builtin_elementwise_fma(G, P, a1v);
                    if (j == 2) a2v = __builtin_elementwise_fma(G, P, a2v);
                    if (j == 3) a3v = __builtin_elementwise_fma(G, P, a3v);
                }
            }
        }
        hS[hs][4 * cg + 0] = a0v;                // conflict-free b128 writes
        hS[hs][4 * cg + 1] = a1v;
        hS[hs][4 * cg + 2] = a2v;
        hS[hs][4 * cg + 3] = a3v;
    };

    // ---- warmup: stage local rows [0,42) -> slots 6..47 (f4 66..527)
    #pragma unroll
    for (int k = 0; k < 2; ++k) {
        int idx = (k << 8) + tid;
        if (idx < 42 * RAWP) {                   // 462
            int o = idx / RAWP, c4 = idx - o * RAWP;
            int db = 6 * RAWP + (k << 8) + (tid & ~63);
            dma1(0, db, R0 + o, c4);
            dma1(1, db, R0 + o, c4);
        }
    }
    asm volatile("s_waitcnt vmcnt(0)" ::: "memory");
    __builtin_amdgcn_s_barrier();
    FENCE();

    // ---- main loop: 8 iterations of 32 output rows
    double tsum = 0.0;
    const int c  = tid & 31;
    const int rb = (tid >> 5) * 4;               // 0,4,...,28
    f4 keep[4];                                  // tail-carry regs (rb>=20)

    for (int i = 0; i < NIT; ++i) {
        if (i >= 1 && i <= NIT - 2) dma_half(i, 0);  // batch A: hides h+v

        // dup-write previous tail (phys 32..41 -> 0..9); h writes 10..41,
        // so rows 0..9 are untouched by htask this phase -> race-free.
        if (i > 0) {
            if (rb == 20) { hS[0][c] = keep[0]; hS[1][c] = keep[1]; }
            if (rb == 24) { hS[2][c] = keep[0]; hS[3][c] = keep[1];
                            hS[4][c] = keep[2]; hS[5][c] = keep[3]; }
            if (rb == 28) { hS[6][c] = keep[0]; hS[7][c] = keep[1];
                            hS[8][c] = keep[2]; hS[9][c] = keep[3]; }
        }

        // h-phase: iter 0 = local rows [0,42) -> phys 0..41 (336 tasks);
        // else rows [32i+10,+42) -> phys 10..41 (256 tasks).
        const int rbm = (i == 0) ? 6 : ((32 * i + 16) % RAWR);
        const int hsb = (i == 0) ? 0 : 10;
        {
            const int cg = (tid >> 3) & 7;
            const int o  = (tid & 7) | ((tid >> 6) << 3);
            htask(o, cg, rbm, hsb);
            if (i == 0) {
                if (tid < 64) htask(32 + (tid & 7), (tid >> 3) & 7, rbm, hsb);
                if (tid < 16) htask(40 + (tid & 1), (tid >> 1) & 7, rbm, hsb);
            }
        }
        asm volatile("s_waitcnt lgkmcnt(0)" ::: "memory");  // publish hS
        __builtin_amdgcn_s_barrier();            // NO vmcnt drain here
        FENCE();
        if (i == 0) dma_half(0, 0);              // iter-0 A: slots busy pre-mid
        if (i <= NIT - 2) dma_half(i, 1);        // batch B: hides under v

        // v-phase: 14 ds_read_b128 at immediate offsets (base = rb*528+c*16,
        // loop-invariant across all 8 iters). Retain phys rows 32..41 into
        // keep[] for next iter's dup (2/4/4 f4 in groups rb=20/24/28).
        f4 A[4];
        #pragma unroll
        for (int j = 0; j < 4; ++j) A[j] = sp(0.f);
        #pragma unroll
        for (int k = 0; k < 14; ++k) {
            f4 v = hS[rb + k][c];                // static immediate offset
            if (rb == 20 && k >= 12) keep[k - 12] = v;   // rows 32,33
            if (rb == 24 && k >= 10) keep[k - 10] = v;   // rows 34..37
            if (rb == 28 && k >= 10) keep[k - 10] = v;   // rows 38..41
            #pragma unroll
            for (int j = 0; j < 4; ++j) {
                int u = k - j;
                if (u >= 0 && u < 11) {
                    f4 G = sp(gw.g[u]);
                    A[j] = __builtin_elementwise_fma(G, v, A[j]);
                }
            }
        }
        const float C1 = 1.0e-4f;
        const float C2 = 9.0e-4f;
        float nn[4], dd[4];
        #pragma unroll
        for (int j = 0; j < 4; ++j) {
            f4 v = A[j];
            float t1 = v.x + 1.f, t2 = v.y + 1.f;        // 2*mu1, 2*mu2
            float num1 = fmaf(t1 * t2, 0.5f, C1);        // 2*mu1*mu2 + C1
            float den1 = fmaf(fmaf(t2, t2, t1 * t1), 0.25f, C1);
            float num2 = fmaf(v.w - v.x * v.y, 0.5f, C2);       // 2*sig12 + C2
            float den2 = fmaf(v.z - fmaf(v.x, v.x, v.y * v.y), 0.25f, C2);
            bool valid = (R0 + 32 * i + rb + j < OH) & (C0 + c < OW);
            nn[j] = valid ? num1 * num2 : 0.f;   // clamped-junk rows land here
            dd[j] = valid ? den1 * den2 : 1.f;   // and are replaced -> safe
        }
        // 1 divide / 4 outputs via common denominator
        // (dd >= C1*C2 ~ 1e-7; 4-products >= ~6e-29 stay normal in f32)
        float d01 = dd[0] * dd[1], d23 = dd[2] * dd[3];
        float s01 = fmaf(nn[0], dd[1], nn[1] * dd[0]);
        float s23 = fmaf(nn[2], dd[3], nn[3] * dd[2]);
        tsum += (double)(fmaf(s01, d23, s23 * d01) / (d01 * d23));

        // end-of-iter: drain DMA (A flew over h+v, B over v) and finish all
        // LDS reads before next iter's h-phase overwrites rows 10..41.
        asm volatile("s_waitcnt vmcnt(0) lgkmcnt(0)" ::: "memory");
        __builtin_amdgcn_s_barrier();
        FENCE();
    }

    // block reduction (double) + one f64 atomic into a strided slot
    #pragma unroll
    for (int off = 32; off > 0; off >>= 1)
        tsum += __shfl_down(tsum, off, 64);
    if ((tid & 63) == 0) wsum[tid >> 6] = tsum;
    __syncthreads();
    if (tid == 0) {
        int slot = (blockIdx.x + blockIdx.y * GX + blockIdx.z * GX * 2)
                   & (NSLOT - 1);
        atomicAdd(&acc[slot * 8], wsum[0] + wsum[1] + wsum[2] + wsum[3]);
    }
}

__global__ void ssim_finalize(const double* __restrict__ acc,
                              float* __restrict__ out) {
    int lane = threadIdx.x;                      // 64 threads, one slot each
    double t = acc[lane * 8];
    #pragma unroll
    for (int off = 32; off > 0; off >>= 1)
        t += __shfl_down(t, off, 64);
    if (lane == 0)
        out[0] = (float)(t * (1.0 / (double)((long long)NC * OH * OW)));
}

extern "C" void kernel_launch(void* const* d_in, const int* in_sizes, int n_in,
                              void* d_out, int out_size, void* d_ws, size_t ws_size,
                              hipStream_t stream) {
    const float* X = (const float*)d_in[0];
    const float* Y = (const float*)d_in[1];
    float* out = (float*)d_out;
    double* acc = (double*)d_ws;                 // 64 slots x 64 B = 4 KB

    // d_ws is re-poisoned to 0xAA before every timed launch: zero the slots.
    hipMemsetAsync(d_ws, 0, NSLOT * 64, stream);

    // Gaussian weights (win=11, sigma=1.5), computed in f64, passed by value.
    GaussW gw;
    {
        double g[11], s = 0.0;
        for (int i = 0; i < 11; ++i) {
            double d = (double)(i - 5);
            g[i] = exp(-d * d / (2.0 * 1.5 * 1.5));
            s += g[i];
        }
        for (int i = 0; i < 11; ++i) gw.g[i] = (float)(g[i] / s);
    }

    dim3 grid(GX, 2, NC);
    ssim_kernel<<<grid, dim3(256), 0, stream>>>(X, Y, acc, gw);
    ssim_finalize<<<1, dim3(64), 0, stream>>>(acc, out);
}